// Round 10
// baseline (444.968 us; speedup 1.0000x reference)
//
#include <hip/hip_runtime.h>

// NT-Xent loss: z_i, z_j [4096,1024] f32 -> scalar f32 loss.
// loss = mean_i( log(sum_{j != i} exp(2*cos_sim(i,j))) - 2*cos_sim(i, i^1) )
//
// R10: R9 + T4 counted-vmcnt pipeline. Three LDS slots (72 KiB, still 2
//      blocks/CU); stage kt+2 at top of kt; WAITVM(6) at bottom drains only
//      stage(kt+1) -> this kt's 6 GLDS stay in flight across the barrier.
//      L2 flight time hidden under a full K-tile body instead of exposed.
//      Frag maps / epilogue / kernels 1,3,4 identical to R9.

#define N_ROWS 8192
#define HALF_N 4096
#define DIMK   1024
#define KTILES 16          // 1024 / 64
#define NJC    64          // 128-wide column panels
#define NTILES 1056        // sum_{jc} (jc/2 + 1)
#define LOGIT_SCALE (2.0f / 256.0f)   // /TEMPERATURE, undo 16*16 fp8 pre-scale

typedef float        f32x16 __attribute__((ext_vector_type(16)));
typedef int          i32x8  __attribute__((ext_vector_type(8)));
typedef unsigned int u32x4  __attribute__((ext_vector_type(4)));

// ---------------- fp8 e4m3 (OCP) conversion, RNE, software ------------------
__device__ __forceinline__ unsigned int f32_to_e4m3(float f) {
    unsigned int b = __float_as_uint(f);
    unsigned int s = (b >> 24) & 0x80u;
    float a = fabsf(f);
    if (a < 0.0009765625f) return s;                  // < 2^-10 -> 0
    if (a < 0.015625f) {                              // subnormal: m * 2^-9
        int q = (int)rintf(a * 512.0f);               // 0..8 (8 -> min normal)
        return s | (unsigned int)q;
    }
    if (a >= 464.0f) return s | 0x7Eu;                // clamp to 448
    int e = (int)((b >> 23) & 0xFF) - 127;            // [-6, 8]
    unsigned int man = b & 0x7FFFFFu;
    unsigned int r = man + 0x7FFFFu + ((man >> 20) & 1u);  // RNE to 3 bits
    unsigned int m8 = r >> 20;
    if (m8 == 8u) { m8 = 0u; ++e; if (e > 8) return s | 0x7Eu; }
    return s | ((unsigned int)(e + 7) << 3) | m8;
}

// ---------------- Kernel 1: row L2-normalize, f32 -> fp8*16 ------------------
__global__ __launch_bounds__(256) void norm_rows_kernel(
    const float* __restrict__ z_i, const float* __restrict__ z_j,
    unsigned int* __restrict__ xn8)   // [8192][256] u32 (=1024 fp8)
{
    const int wave = threadIdx.x >> 6, lane = threadIdx.x & 63;
    const int row = blockIdx.x * 4 + wave;
    const float* src = (row < HALF_N) ? (z_i + (size_t)row * DIMK)
                                      : (z_j + (size_t)(row - HALF_N) * DIMK);
    float4 v[4];
    float ss = 0.0f;
    #pragma unroll
    for (int i = 0; i < 4; ++i) {
        v[i] = ((const float4*)src)[i * 64 + lane];
        ss += v[i].x * v[i].x + v[i].y * v[i].y + v[i].z * v[i].z + v[i].w * v[i].w;
    }
    #pragma unroll
    for (int m = 1; m < 64; m <<= 1) ss += __shfl_xor(ss, m, 64);
    const float rn = 16.0f / fmaxf(sqrtf(ss), 1e-8f);   // x16 fp8 pre-scale

    unsigned int* dst = xn8 + (size_t)row * (DIMK / 4);
    #pragma unroll
    for (int i = 0; i < 4; ++i) {
        unsigned int p = f32_to_e4m3(v[i].x * rn)
                       | (f32_to_e4m3(v[i].y * rn) << 8)
                       | (f32_to_e4m3(v[i].z * rn) << 16)
                       | (f32_to_e4m3(v[i].w * rn) << 24);
        dst[i * 64 + lane] = p;
    }
}

// ---- Kernel 2: fused sim-GEMM (MX-fp8 32x32x64) + exp row/col sums ----------
#define BAR() do { asm volatile("" ::: "memory"); \
                   __builtin_amdgcn_s_barrier();  \
                   asm volatile("" ::: "memory"); } while (0)
#define WAITVM6() asm volatile("s_waitcnt vmcnt(6)" ::: "memory")
#define WAITVM0() asm volatile("s_waitcnt vmcnt(0)" ::: "memory")
#define GLDS(gp, lp) __builtin_amdgcn_global_load_lds(                          \
        (const __attribute__((address_space(1))) void*)(gp),                    \
        (__attribute__((address_space(3))) void*)(lp), 16, 0, 0)

// LDS placement (R9): pair two 64-B rows into a 128-B window, XOR chunk pos:
// unit(r,c) = (r>>1)*8 + ((((r&1)<<2)|c) ^ ((r>>1)&7)). Bijective; frag reads
// phase-uniform; GLDS sources = 64-B coalesced segments.
__device__ __forceinline__ int unit_of(int r, int c) {
    return ((r >> 1) << 3) + (((((r & 1) << 2) | c)) ^ ((r >> 1) & 7));
}

__global__ __launch_bounds__(256, 2) void simexp_kernel(
    const unsigned char* __restrict__ xn8,
    float* __restrict__ rs,     // [128][N_ROWS] planes: jc*2 + wn
    float* __restrict__ cs,     // [64][N_ROWS]  planes: rt*2 + wm
    float* __restrict__ tgt)    // [N_ROWS]
{
    __shared__ u32x4 Abuf[3][1024];   // 3 x 16 KiB (256 rows x 4 chunks)
    __shared__ u32x4 Bbuf[3][512];    // 3 x  8 KiB (128 rows x 4 chunks)

    // bijective XCD swizzle: 1056 = 8 * 132
    const int orig = blockIdx.x;
    const int bid  = (orig & 7) * 132 + (orig >> 3);

    // decode (rt, jc): tiles ordered jc-major, rt = 0..jc/2
    int rem = bid, jc = 0;
    for (;;) { const int cnt = (jc >> 1) + 1; if (rem < cnt) break; rem -= cnt; ++jc; }
    const int rt = rem;

    const int t = threadIdx.x;
    const int lane = t & 63, wave = t >> 6;
    const int wm = wave >> 1, wn = wave & 1;     // 2x2 wave grid
    const int rowBase = rt * 256, colBase = jc * 128;
    const int l31 = lane & 31, h = lane >> 5;

    f32x16 acc[4][2];
    #pragma unroll
    for (int i = 0; i < 4; ++i)
        #pragma unroll
        for (int j = 0; j < 2; ++j)
            #pragma unroll
            for (int v = 0; v < 16; ++v) acc[i][j][v] = 0.0f;

    // staging: unit u = s_*256 + t (linear LDS dest); inverse map:
    // r2 = u>>3, y = (u&7) ^ (r2&7), row = 2*r2 + (y>>2), chunk = y&3.
#define STAGE_TILE(SLOT, KT) do {                                                \
        _Pragma("unroll")                                                        \
        for (int s_ = 0; s_ < 4; ++s_) {                                         \
            const int u_  = s_ * 256 + t;                                        \
            const int r2_ = u_ >> 3;                                             \
            const int y_  = (u_ & 7) ^ (r2_ & 7);                                \
            const int rl_ = 2 * r2_ + (y_ >> 2);                                 \
            const unsigned char* g = xn8 +                                       \
                (size_t)(rowBase + rl_) * DIMK + (KT) * 64 + (y_ & 3) * 16;      \
            GLDS(g, &Abuf[SLOT][s_ * 256 + wave * 64]);                          \
        }                                                                        \
        _Pragma("unroll")                                                        \
        for (int s_ = 0; s_ < 2; ++s_) {                                         \
            const int u_  = s_ * 256 + t;                                        \
            const int r2_ = u_ >> 3;                                             \
            const int y_  = (u_ & 7) ^ (r2_ & 7);                                \
            const int rl_ = 2 * r2_ + (y_ >> 2);                                 \
            const unsigned char* g = xn8 +                                       \
                (size_t)(colBase + rl_) * DIMK + (KT) * 64 + (y_ & 3) * 16;      \
            GLDS(g, &Bbuf[SLOT][s_ * 256 + wave * 64]);                          \
        }                                                                        \
    } while (0)

    // compute body for one K-tile from slot S (6 frag-read pairs + 8 MFMA)
#define COMPUTE(S) do {                                                          \
        union Frag { u32x4 q[2]; i32x8 v; };                                     \
        i32x8 af[4], bf[2];                                                      \
        _Pragma("unroll")                                                        \
        for (int fi = 0; fi < 4; ++fi) {                                         \
            const int r = wm * 128 + fi * 32 + l31;                              \
            Frag fa;                                                             \
            fa.q[0] = Abuf[S][unit_of(r, 2 * h)];                                \
            fa.q[1] = Abuf[S][unit_of(r, 2 * h + 1)];                            \
            af[fi] = fa.v;                                                       \
        }                                                                        \
        _Pragma("unroll")                                                        \
        for (int cf = 0; cf < 2; ++cf) {                                         \
            const int r = wn * 64 + cf * 32 + l31;                               \
            Frag fb;                                                             \
            fb.q[0] = Bbuf[S][unit_of(r, 2 * h)];                                \
            fb.q[1] = Bbuf[S][unit_of(r, 2 * h + 1)];                            \
            bf[cf] = fb.v;                                                       \
        }                                                                        \
        __builtin_amdgcn_s_setprio(1);                                           \
        _Pragma("unroll")                                                        \
        for (int fi = 0; fi < 4; ++fi)                                           \
            _Pragma("unroll")                                                    \
            for (int cf = 0; cf < 2; ++cf)                                       \
                acc[fi][cf] = __builtin_amdgcn_mfma_scale_f32_32x32x64_f8f6f4(   \
                    af[fi], bf[cf], acc[fi][cf], 0, 0,                           \
                    0, 0x7F7F7F7F, 0, 0x7F7F7F7F);                               \
        __builtin_amdgcn_s_setprio(0);                                           \
    } while (0)

    // prologue: stage kt0 -> slot0, kt1 -> slot1; wait only for kt0 (6 left)
    STAGE_TILE(0, 0);
    STAGE_TILE(1, 1);
    WAITVM6();
    BAR();

    int s_read = 0, s_mid = 1, s_write = 2;
    // main loop: kt = 0..13 (stage kt+2, counted wait for kt+1)
    for (int kt = 0; kt < KTILES - 2; ++kt) {
        STAGE_TILE(s_write, kt + 2);
        COMPUTE(s_read);
        WAITVM6();              // drain stage(kt+1); stage(kt+2) stays in flight
        BAR();
        const int tmp = s_read; s_read = s_mid; s_mid = s_write; s_write = tmp;
    }
    // kt = 14: no stage; drain stage(15)
    COMPUTE(s_read);
    WAITVM0();
    BAR();
    { const int tmp = s_read; s_read = s_mid; s_mid = s_write; s_write = tmp; }
    // kt = 15: compute only
    COMPUTE(s_read);
#undef STAGE_TILE
#undef COMPUTE

    // ---- epilogue ----
    // C/D 32x32 layout (m74/m101): col = lane&31, row = (v&3)+8*(v>>2)+4*(lane>>5)
    float cspart[2] = {0.0f, 0.0f};
    #pragma unroll
    for (int fi = 0; fi < 4; ++fi) {
        float rpart[16];
        #pragma unroll
        for (int v = 0; v < 16; ++v) rpart[v] = 0.0f;
        #pragma unroll
        for (int cf = 0; cf < 2; ++cf) {
            const int gcol = colBase + wn * 64 + cf * 32 + l31;
            #pragma unroll
            for (int v = 0; v < 16; ++v) {
                const int grow = rowBase + wm * 128 + fi * 32
                               + (v & 3) + 8 * (v >> 2) + 4 * h;
                const float tv = acc[fi][cf][v] * LOGIT_SCALE;
                if (gcol == grow + 1 && ((grow & 1) == 0)) {
                    tgt[grow] = tv; tgt[grow + 1] = tv;   // sim symmetric
                }
                const float ev = (gcol > grow) ? __expf(tv) : 0.0f;
                rpart[v] += ev;
                cspart[cf] += ev;
            }
        }
        // row sums: reduce over the 32 columns (lanes sharing l>>5)
        #pragma unroll
        for (int m = 1; m < 32; m <<= 1) {
            #pragma unroll
            for (int v = 0; v < 16; ++v) rpart[v] += __shfl_xor(rpart[v], m, 64);
        }
        if (l31 == 0) {
            float* dst = rs + (size_t)(jc * 2 + wn) * N_ROWS;
            #pragma unroll
            for (int v = 0; v < 16; ++v)
                dst[rowBase + wm * 128 + fi * 32 + (v & 3) + 8 * (v >> 2) + 4 * h]
                    = rpart[v];
        }
    }
    // column sums (mirror): combine lane halves, lanes 0-31 write
    #pragma unroll
    for (int cf = 0; cf < 2; ++cf) {
        cspart[cf] += __shfl_xor(cspart[cf], 32, 64);
        if (lane < 32)
            cs[(size_t)(rt * 2 + wm) * N_ROWS + colBase + wn * 64 + cf * 32 + l31]
                = cspart[cf];
    }
}

// ------------- Kernel 3: per-row LSE - target logit --------------------------
// row x: rs planes jc*2+{0,1} for jc >= 2*(x>>8); cs planes rt*2+{0,1} for
// rt <= (x>>7)/2  (exactly the tiles that exist for this row/col).
__global__ __launch_bounds__(256) void row_term_kernel(
    const float* __restrict__ rs, const float* __restrict__ cs,
    const float* __restrict__ tgt, float* __restrict__ terms)
{
    const int row = blockIdx.x * 256 + threadIdx.x;
    const int P = row >> 8, jcx = row >> 7;
    float s = 0.0f;
    for (int jc = 2 * P; jc < NJC; ++jc) {
        const float* b = rs + (size_t)(jc * 2) * N_ROWS + row;
        s += b[0] + b[N_ROWS];
    }
    for (int rt = 0; rt <= (jcx >> 1); ++rt) {
        const float* b = cs + (size_t)(rt * 2) * N_ROWS + row;
        s += b[0] + b[N_ROWS];
    }
    terms[row] = logf(s) - tgt[row];
}

// ------------- Kernel 4: mean over rows --------------------------------------
__global__ __launch_bounds__(256) void loss_kernel(
    const float* __restrict__ terms, float* __restrict__ out)
{
    const int t = threadIdx.x;
    float s = 0.0f;
    for (int i = t; i < N_ROWS; i += 256) s += terms[i];
    #pragma unroll
    for (int m = 1; m < 64; m <<= 1) s += __shfl_xor(s, m, 64);
    __shared__ float red[4];
    if ((t & 63) == 0) red[t >> 6] = s;
    __syncthreads();
    if (t == 0) out[0] = (red[0] + red[1] + red[2] + red[3]) * (1.0f / N_ROWS);
}

extern "C" void kernel_launch(void* const* d_in, const int* in_sizes, int n_in,
                              void* d_out, int out_size, void* d_ws, size_t ws_size,
                              hipStream_t stream)
{
    const float* z_i = (const float*)d_in[0];
    const float* z_j = (const float*)d_in[1];
    float* out = (float*)d_out;

    // workspace layout
    unsigned char* xn8 = (unsigned char*)d_ws;                        // 8 MiB fp8
    float* rs    = (float*)(xn8 + (size_t)N_ROWS * DIMK);             // 4 MiB
    float* cs    = rs + (size_t)128 * N_ROWS;                         // 2 MiB
    float* tgt   = cs + (size_t)64 * N_ROWS;                          // 32 KiB
    float* terms = tgt + N_ROWS;                                      // 32 KiB

    norm_rows_kernel<<<N_ROWS / 4, 256, 0, stream>>>(z_i, z_j, (unsigned int*)xn8);
    simexp_kernel<<<NTILES, 256, 0, stream>>>(xn8, rs, cs, tgt);
    row_term_kernel<<<N_ROWS / 256, 256, 0, stream>>>(rs, cs, tgt, terms);
    loss_kernel<<<1, 256, 0, stream>>>(terms, out);
}

// Round 11
// 111.296 us; speedup vs baseline: 3.9980x; 3.9980x over previous
//
#include <hip/hip_runtime.h>

// NT-Xent loss: z_i, z_j [4096,1024] f32 -> scalar f32 loss.
// loss = mean_i( log(sum_{j != i} exp(2*cos_sim(i,j))) - 2*cos_sim(i, i^1) )
//
// R11: R9 (clean 114.7us point) with ONE change: K-loop body reordered to
//      {frag ds_reads -> STAGE(kt+1) -> MFMA -> vmcnt(0) -> barrier} so the
//      compiler's conservative vmcnt(0)-before-ds_read (LDS alias safety vs
//      in-flight global_load_lds) no longer serializes the stage's L2 flight
//      into every K-tile. 2 slots, same maps, same epilogue, same kernels.

#define N_ROWS 8192
#define HALF_N 4096
#define DIMK   1024
#define KTILES 16          // 1024 / 64
#define NJC    64          // 128-wide column panels
#define NTILES 1056        // sum_{jc} (jc/2 + 1)
#define LOGIT_SCALE (2.0f / 256.0f)   // /TEMPERATURE, undo 16*16 fp8 pre-scale

typedef float        f32x16 __attribute__((ext_vector_type(16)));
typedef int          i32x8  __attribute__((ext_vector_type(8)));
typedef unsigned int u32x4  __attribute__((ext_vector_type(4)));

// ---------------- fp8 e4m3 (OCP) conversion, RNE, software ------------------
__device__ __forceinline__ unsigned int f32_to_e4m3(float f) {
    unsigned int b = __float_as_uint(f);
    unsigned int s = (b >> 24) & 0x80u;
    float a = fabsf(f);
    if (a < 0.0009765625f) return s;                  // < 2^-10 -> 0
    if (a < 0.015625f) {                              // subnormal: m * 2^-9
        int q = (int)rintf(a * 512.0f);               // 0..8 (8 -> min normal)
        return s | (unsigned int)q;
    }
    if (a >= 464.0f) return s | 0x7Eu;                // clamp to 448
    int e = (int)((b >> 23) & 0xFF) - 127;            // [-6, 8]
    unsigned int man = b & 0x7FFFFFu;
    unsigned int r = man + 0x7FFFFu + ((man >> 20) & 1u);  // RNE to 3 bits
    unsigned int m8 = r >> 20;
    if (m8 == 8u) { m8 = 0u; ++e; if (e > 8) return s | 0x7Eu; }
    return s | ((unsigned int)(e + 7) << 3) | m8;
}

// ---------------- Kernel 1: row L2-normalize, f32 -> fp8*16 ------------------
// one wave per row; 4 waves per block
__global__ __launch_bounds__(256) void norm_rows_kernel(
    const float* __restrict__ z_i, const float* __restrict__ z_j,
    unsigned int* __restrict__ xn8)   // [8192][256] u32 (=1024 fp8)
{
    const int wave = threadIdx.x >> 6, lane = threadIdx.x & 63;
    const int row = blockIdx.x * 4 + wave;
    const float* src = (row < HALF_N) ? (z_i + (size_t)row * DIMK)
                                      : (z_j + (size_t)(row - HALF_N) * DIMK);
    float4 v[4];
    float ss = 0.0f;
    #pragma unroll
    for (int i = 0; i < 4; ++i) {
        v[i] = ((const float4*)src)[i * 64 + lane];
        ss += v[i].x * v[i].x + v[i].y * v[i].y + v[i].z * v[i].z + v[i].w * v[i].w;
    }
    #pragma unroll
    for (int m = 1; m < 64; m <<= 1) ss += __shfl_xor(ss, m, 64);
    const float rn = 16.0f / fmaxf(sqrtf(ss), 1e-8f);   // x16 fp8 pre-scale

    unsigned int* dst = xn8 + (size_t)row * (DIMK / 4);
    #pragma unroll
    for (int i = 0; i < 4; ++i) {
        unsigned int p = f32_to_e4m3(v[i].x * rn)
                       | (f32_to_e4m3(v[i].y * rn) << 8)
                       | (f32_to_e4m3(v[i].z * rn) << 16)
                       | (f32_to_e4m3(v[i].w * rn) << 24);
        dst[i * 64 + lane] = p;
    }
}

// ---- Kernel 2: fused sim-GEMM (MX-fp8 32x32x64) + exp row/col sums ----------
#define BAR() do { asm volatile("" ::: "memory"); \
                   __builtin_amdgcn_s_barrier();  \
                   asm volatile("" ::: "memory"); } while (0)
#define WAITVM0() asm volatile("s_waitcnt vmcnt(0)" ::: "memory")
#define GLDS(gp, lp) __builtin_amdgcn_global_load_lds(                          \
        (const __attribute__((address_space(1))) void*)(gp),                    \
        (__attribute__((address_space(3))) void*)(lp), 16, 0, 0)

// LDS placement (R9): pair two 64-B rows into a 128-B window, XOR chunk pos:
// unit(r,c) = (r>>1)*8 + ((((r&1)<<2)|c) ^ ((r>>1)&7)). Bijective; frag reads
// phase-uniform; GLDS sources = 64-B coalesced segments.
__device__ __forceinline__ int unit_of(int r, int c) {
    return ((r >> 1) << 3) + (((((r & 1) << 2) | c)) ^ ((r >> 1) & 7));
}

__global__ __launch_bounds__(256, 2) void simexp_kernel(
    const unsigned char* __restrict__ xn8,
    float* __restrict__ rs,     // [128][N_ROWS] planes: jc*2 + wn
    float* __restrict__ cs,     // [64][N_ROWS]  planes: rt*2 + wm
    float* __restrict__ tgt)    // [N_ROWS]
{
    __shared__ u32x4 Abuf[2][1024];   // 2 x 16 KiB (256 rows x 4 chunks)
    __shared__ u32x4 Bbuf[2][512];    // 2 x  8 KiB (128 rows x 4 chunks)

    // bijective XCD swizzle: 1056 = 8 * 132
    const int orig = blockIdx.x;
    const int bid  = (orig & 7) * 132 + (orig >> 3);

    // decode (rt, jc): tiles ordered jc-major, rt = 0..jc/2
    int rem = bid, jc = 0;
    for (;;) { const int cnt = (jc >> 1) + 1; if (rem < cnt) break; rem -= cnt; ++jc; }
    const int rt = rem;

    const int t = threadIdx.x;
    const int lane = t & 63, wave = t >> 6;
    const int wm = wave >> 1, wn = wave & 1;     // 2x2 wave grid
    const int rowBase = rt * 256, colBase = jc * 128;
    const int l31 = lane & 31, h = lane >> 5;

    f32x16 acc[4][2];
    #pragma unroll
    for (int i = 0; i < 4; ++i)
        #pragma unroll
        for (int j = 0; j < 2; ++j)
            #pragma unroll
            for (int v = 0; v < 16; ++v) acc[i][j][v] = 0.0f;

    // staging: unit u = s_*256 + t (linear LDS dest); inverse map:
    // r2 = u>>3, y = (u&7) ^ (r2&7), row = 2*r2 + (y>>2), chunk = y&3.
#define STAGE_TILE(SLOT, KT) do {                                                \
        _Pragma("unroll")                                                        \
        for (int s_ = 0; s_ < 4; ++s_) {                                         \
            const int u_  = s_ * 256 + t;                                        \
            const int r2_ = u_ >> 3;                                             \
            const int y_  = (u_ & 7) ^ (r2_ & 7);                                \
            const int rl_ = 2 * r2_ + (y_ >> 2);                                 \
            const unsigned char* g = xn8 +                                       \
                (size_t)(rowBase + rl_) * DIMK + (KT) * 64 + (y_ & 3) * 16;      \
            GLDS(g, &Abuf[SLOT][s_ * 256 + wave * 64]);                          \
        }                                                                        \
        _Pragma("unroll")                                                        \
        for (int s_ = 0; s_ < 2; ++s_) {                                         \
            const int u_  = s_ * 256 + t;                                        \
            const int r2_ = u_ >> 3;                                             \
            const int y_  = (u_ & 7) ^ (r2_ & 7);                                \
            const int rl_ = 2 * r2_ + (y_ >> 2);                                 \
            const unsigned char* g = xn8 +                                       \
                (size_t)(colBase + rl_) * DIMK + (KT) * 64 + (y_ & 3) * 16;      \
            GLDS(g, &Bbuf[SLOT][s_ * 256 + wave * 64]);                          \
        }                                                                        \
    } while (0)

    // prologue: tile 0 into slot 0
    STAGE_TILE(0, 0);
    WAITVM0();
    BAR();

    int slot = 0;
    for (int kt = 0; kt < KTILES; ++kt) {
        const bool nx = (kt + 1 < KTILES);

        // ---- frag reads FIRST (vmcnt already 0 here -> no forced drain) ----
        union Frag { u32x4 q[2]; i32x8 v; };
        i32x8 af[4], bf[2];
        #pragma unroll
        for (int fi = 0; fi < 4; ++fi) {
            const int r = wm * 128 + fi * 32 + l31;
            Frag fa;
            fa.q[0] = Abuf[slot][unit_of(r, 2 * h)];
            fa.q[1] = Abuf[slot][unit_of(r, 2 * h + 1)];
            af[fi] = fa.v;
        }
        #pragma unroll
        for (int cf = 0; cf < 2; ++cf) {
            const int r = wn * 64 + cf * 32 + l31;
            Frag fb;
            fb.q[0] = Bbuf[slot][unit_of(r, 2 * h)];
            fb.q[1] = Bbuf[slot][unit_of(r, 2 * h + 1)];
            bf[cf] = fb.v;
        }

        // ---- stage kt+1 AFTER the reads (flight hides under MFMAs) ----
        if (nx) STAGE_TILE(slot ^ 1, kt + 1);

        __builtin_amdgcn_s_setprio(1);
        #pragma unroll
        for (int fi = 0; fi < 4; ++fi)
            #pragma unroll
            for (int cf = 0; cf < 2; ++cf)
                acc[fi][cf] = __builtin_amdgcn_mfma_scale_f32_32x32x64_f8f6f4(
                    af[fi], bf[cf], acc[fi][cf], 0, 0,
                    0, 0x7F7F7F7F, 0, 0x7F7F7F7F);   // fmt=fp8, scales=1.0
        __builtin_amdgcn_s_setprio(0);

        if (nx) {
            WAITVM0();      // drain stage(kt+1) after MFMA issue window
            BAR();
        }
        slot ^= 1;
    }
#undef STAGE_TILE

    // ---- epilogue ----
    // C/D 32x32 layout (m74/m101): col = lane&31, row = (v&3)+8*(v>>2)+4*(lane>>5)
    float cspart[2] = {0.0f, 0.0f};
    #pragma unroll
    for (int fi = 0; fi < 4; ++fi) {
        float rpart[16];
        #pragma unroll
        for (int v = 0; v < 16; ++v) rpart[v] = 0.0f;
        #pragma unroll
        for (int cf = 0; cf < 2; ++cf) {
            const int gcol = colBase + wn * 64 + cf * 32 + l31;
            #pragma unroll
            for (int v = 0; v < 16; ++v) {
                const int grow = rowBase + wm * 128 + fi * 32
                               + (v & 3) + 8 * (v >> 2) + 4 * h;
                const float tv = acc[fi][cf][v] * LOGIT_SCALE;
                if (gcol == grow + 1 && ((grow & 1) == 0)) {
                    tgt[grow] = tv; tgt[grow + 1] = tv;   // sim symmetric
                }
                const float ev = (gcol > grow) ? __expf(tv) : 0.0f;
                rpart[v] += ev;
                cspart[cf] += ev;
            }
        }
        // row sums: reduce over the 32 columns (lanes sharing l>>5)
        #pragma unroll
        for (int m = 1; m < 32; m <<= 1) {
            #pragma unroll
            for (int v = 0; v < 16; ++v) rpart[v] += __shfl_xor(rpart[v], m, 64);
        }
        if (l31 == 0) {
            float* dst = rs + (size_t)(jc * 2 + wn) * N_ROWS;
            #pragma unroll
            for (int v = 0; v < 16; ++v)
                dst[rowBase + wm * 128 + fi * 32 + (v & 3) + 8 * (v >> 2) + 4 * h]
                    = rpart[v];
        }
    }
    // column sums (mirror): combine lane halves, lanes 0-31 write
    #pragma unroll
    for (int cf = 0; cf < 2; ++cf) {
        cspart[cf] += __shfl_xor(cspart[cf], 32, 64);
        if (lane < 32)
            cs[(size_t)(rt * 2 + wm) * N_ROWS + colBase + wn * 64 + cf * 32 + l31]
                = cspart[cf];
    }
}

// ------------- Kernel 3: per-row LSE - target logit --------------------------
// row x: rs planes jc*2+{0,1} for jc >= 2*(x>>8); cs planes rt*2+{0,1} for
// rt <= (x>>7)/2  (exactly the tiles that exist for this row/col).
__global__ __launch_bounds__(256) void row_term_kernel(
    const float* __restrict__ rs, const float* __restrict__ cs,
    const float* __restrict__ tgt, float* __restrict__ terms)
{
    const int row = blockIdx.x * 256 + threadIdx.x;
    const int P = row >> 8, jcx = row >> 7;
    float s = 0.0f;
    for (int jc = 2 * P; jc < NJC; ++jc) {
        const float* b = rs + (size_t)(jc * 2) * N_ROWS + row;
        s += b[0] + b[N_ROWS];
    }
    for (int rt = 0; rt <= (jcx >> 1); ++rt) {
        const float* b = cs + (size_t)(rt * 2) * N_ROWS + row;
        s += b[0] + b[N_ROWS];
    }
    terms[row] = logf(s) - tgt[row];
}

// ------------- Kernel 4: mean over rows --------------------------------------
__global__ __launch_bounds__(256) void loss_kernel(
    const float* __restrict__ terms, float* __restrict__ out)
{
    const int t = threadIdx.x;
    float s = 0.0f;
    for (int i = t; i < N_ROWS; i += 256) s += terms[i];
    #pragma unroll
    for (int m = 1; m < 64; m <<= 1) s += __shfl_xor(s, m, 64);
    __shared__ float red[4];
    if ((t & 63) == 0) red[t >> 6] = s;
    __syncthreads();
    if (t == 0) out[0] = (red[0] + red[1] + red[2] + red[3]) * (1.0f / N_ROWS);
}

extern "C" void kernel_launch(void* const* d_in, const int* in_sizes, int n_in,
                              void* d_out, int out_size, void* d_ws, size_t ws_size,
                              hipStream_t stream)
{
    const float* z_i = (const float*)d_in[0];
    const float* z_j = (const float*)d_in[1];
    float* out = (float*)d_out;

    // workspace layout
    unsigned char* xn8 = (unsigned char*)d_ws;                        // 8 MiB fp8
    float* rs    = (float*)(xn8 + (size_t)N_ROWS * DIMK);             // 4 MiB
    float* cs    = rs + (size_t)128 * N_ROWS;                         // 2 MiB
    float* tgt   = cs + (size_t)64 * N_ROWS;                          // 32 KiB
    float* terms = tgt + N_ROWS;                                      // 32 KiB

    norm_rows_kernel<<<N_ROWS / 4, 256, 0, stream>>>(z_i, z_j, (unsigned int*)xn8);
    simexp_kernel<<<NTILES, 256, 0, stream>>>(xn8, rs, cs, tgt);
    row_term_kernel<<<N_ROWS / 256, 256, 0, stream>>>(rs, cs, tgt, terms);
    loss_kernel<<<1, 256, 0, stream>>>(terms, out);
}

// Round 12
// 99.805 us; speedup vs baseline: 4.4584x; 1.1151x over previous
//
#include <hip/hip_runtime.h>

// NT-Xent loss: z_i, z_j [4096,1024] f32 -> scalar f32 loss.
// loss = mean_i( log(sum_{j != i} exp(2*cos_sim(i,j))) - 2*cos_sim(i, i^1) )
//
// R12: simexp kernel byte-identical to R11 (71.3us clean point). Changes:
//      - norm_rows: HW packed fp8 convert (v_cvt_pk_fp8_f32, OCP+RNE on
//        gfx950) replaces the branchy software e4m3 path (8.4M conversions).
//        __has_builtin-guarded with software fallback.
//      - loss_kernel: 1024 threads (was 256) to cut the single-block tail.

#define N_ROWS 8192
#define HALF_N 4096
#define DIMK   1024
#define KTILES 16          // 1024 / 64
#define NJC    64          // 128-wide column panels
#define NTILES 1056        // sum_{jc} (jc/2 + 1)
#define LOGIT_SCALE (2.0f / 256.0f)   // /TEMPERATURE, undo 16*16 fp8 pre-scale

typedef float        f32x16 __attribute__((ext_vector_type(16)));
typedef int          i32x8  __attribute__((ext_vector_type(8)));
typedef unsigned int u32x4  __attribute__((ext_vector_type(4)));

// ---------------- fp8 e4m3 (OCP) conversion ---------------------------------
__device__ __forceinline__ unsigned int f32_to_e4m3_sw(float f) {
    unsigned int b = __float_as_uint(f);
    unsigned int s = (b >> 24) & 0x80u;
    float a = fabsf(f);
    if (a < 0.0009765625f) return s;                  // < 2^-10 -> 0
    if (a < 0.015625f) {                              // subnormal: m * 2^-9
        int q = (int)rintf(a * 512.0f);               // 0..8 (8 -> min normal)
        return s | (unsigned int)q;
    }
    if (a >= 464.0f) return s | 0x7Eu;                // clamp to 448
    int e = (int)((b >> 23) & 0xFF) - 127;            // [-6, 8]
    unsigned int man = b & 0x7FFFFFu;
    unsigned int r = man + 0x7FFFFu + ((man >> 20) & 1u);  // RNE to 3 bits
    unsigned int m8 = r >> 20;
    if (m8 == 8u) { m8 = 0u; ++e; if (e > 8) return s | 0x7Eu; }
    return s | ((unsigned int)(e + 7) << 3) | m8;
}

__device__ __forceinline__ unsigned int pack4_e4m3(float x, float y,
                                                   float z, float w) {
#if __has_builtin(__builtin_amdgcn_cvt_pk_fp8_f32)
    int p = __builtin_amdgcn_cvt_pk_fp8_f32(x, y, 0, false);   // low word
    p     = __builtin_amdgcn_cvt_pk_fp8_f32(z, w, p, true);    // high word
    return (unsigned int)p;
#else
    return f32_to_e4m3_sw(x) | (f32_to_e4m3_sw(y) << 8)
         | (f32_to_e4m3_sw(z) << 16) | (f32_to_e4m3_sw(w) << 24);
#endif
}

// ---------------- Kernel 1: row L2-normalize, f32 -> fp8*16 ------------------
// one wave per row; 4 waves per block
__global__ __launch_bounds__(256) void norm_rows_kernel(
    const float* __restrict__ z_i, const float* __restrict__ z_j,
    unsigned int* __restrict__ xn8)   // [8192][256] u32 (=1024 fp8)
{
    const int wave = threadIdx.x >> 6, lane = threadIdx.x & 63;
    const int row = blockIdx.x * 4 + wave;
    const float* src = (row < HALF_N) ? (z_i + (size_t)row * DIMK)
                                      : (z_j + (size_t)(row - HALF_N) * DIMK);
    float4 v[4];
    float ss = 0.0f;
    #pragma unroll
    for (int i = 0; i < 4; ++i) {
        v[i] = ((const float4*)src)[i * 64 + lane];
        ss += v[i].x * v[i].x + v[i].y * v[i].y + v[i].z * v[i].z + v[i].w * v[i].w;
    }
    #pragma unroll
    for (int m = 1; m < 64; m <<= 1) ss += __shfl_xor(ss, m, 64);
    const float rn = 16.0f / fmaxf(sqrtf(ss), 1e-8f);   // x16 fp8 pre-scale

    unsigned int* dst = xn8 + (size_t)row * (DIMK / 4);
    #pragma unroll
    for (int i = 0; i < 4; ++i)
        dst[i * 64 + lane] = pack4_e4m3(v[i].x * rn, v[i].y * rn,
                                        v[i].z * rn, v[i].w * rn);
}

// ---- Kernel 2: fused sim-GEMM (MX-fp8 32x32x64) + exp row/col sums ----------
#define BAR() do { asm volatile("" ::: "memory"); \
                   __builtin_amdgcn_s_barrier();  \
                   asm volatile("" ::: "memory"); } while (0)
#define WAITVM0() asm volatile("s_waitcnt vmcnt(0)" ::: "memory")
#define GLDS(gp, lp) __builtin_amdgcn_global_load_lds(                          \
        (const __attribute__((address_space(1))) void*)(gp),                    \
        (__attribute__((address_space(3))) void*)(lp), 16, 0, 0)

// LDS placement (R9): pair two 64-B rows into a 128-B window, XOR chunk pos:
// unit(r,c) = (r>>1)*8 + ((((r&1)<<2)|c) ^ ((r>>1)&7)). Bijective; frag reads
// phase-uniform; GLDS sources = 64-B coalesced segments.
__device__ __forceinline__ int unit_of(int r, int c) {
    return ((r >> 1) << 3) + (((((r & 1) << 2) | c)) ^ ((r >> 1) & 7));
}

__global__ __launch_bounds__(256, 2) void simexp_kernel(
    const unsigned char* __restrict__ xn8,
    float* __restrict__ rs,     // [128][N_ROWS] planes: jc*2 + wn
    float* __restrict__ cs,     // [64][N_ROWS]  planes: rt*2 + wm
    float* __restrict__ tgt)    // [N_ROWS]
{
    __shared__ u32x4 Abuf[2][1024];   // 2 x 16 KiB (256 rows x 4 chunks)
    __shared__ u32x4 Bbuf[2][512];    // 2 x  8 KiB (128 rows x 4 chunks)

    // bijective XCD swizzle: 1056 = 8 * 132
    const int orig = blockIdx.x;
    const int bid  = (orig & 7) * 132 + (orig >> 3);

    // decode (rt, jc): tiles ordered jc-major, rt = 0..jc/2
    int rem = bid, jc = 0;
    for (;;) { const int cnt = (jc >> 1) + 1; if (rem < cnt) break; rem -= cnt; ++jc; }
    const int rt = rem;

    const int t = threadIdx.x;
    const int lane = t & 63, wave = t >> 6;
    const int wm = wave >> 1, wn = wave & 1;     // 2x2 wave grid
    const int rowBase = rt * 256, colBase = jc * 128;
    const int l31 = lane & 31, h = lane >> 5;

    f32x16 acc[4][2];
    #pragma unroll
    for (int i = 0; i < 4; ++i)
        #pragma unroll
        for (int j = 0; j < 2; ++j)
            #pragma unroll
            for (int v = 0; v < 16; ++v) acc[i][j][v] = 0.0f;

    // staging: unit u = s_*256 + t (linear LDS dest); inverse map:
    // r2 = u>>3, y = (u&7) ^ (r2&7), row = 2*r2 + (y>>2), chunk = y&3.
#define STAGE_TILE(SLOT, KT) do {                                                \
        _Pragma("unroll")                                                        \
        for (int s_ = 0; s_ < 4; ++s_) {                                         \
            const int u_  = s_ * 256 + t;                                        \
            const int r2_ = u_ >> 3;                                             \
            const int y_  = (u_ & 7) ^ (r2_ & 7);                                \
            const int rl_ = 2 * r2_ + (y_ >> 2);                                 \
            const unsigned char* g = xn8 +                                       \
                (size_t)(rowBase + rl_) * DIMK + (KT) * 64 + (y_ & 3) * 16;      \
            GLDS(g, &Abuf[SLOT][s_ * 256 + wave * 64]);                          \
        }                                                                        \
        _Pragma("unroll")                                                        \
        for (int s_ = 0; s_ < 2; ++s_) {                                         \
            const int u_  = s_ * 256 + t;                                        \
            const int r2_ = u_ >> 3;                                             \
            const int y_  = (u_ & 7) ^ (r2_ & 7);                                \
            const int rl_ = 2 * r2_ + (y_ >> 2);                                 \
            const unsigned char* g = xn8 +                                       \
                (size_t)(colBase + rl_) * DIMK + (KT) * 64 + (y_ & 3) * 16;      \
            GLDS(g, &Bbuf[SLOT][s_ * 256 + wave * 64]);                          \
        }                                                                        \
    } while (0)

    // prologue: tile 0 into slot 0
    STAGE_TILE(0, 0);
    WAITVM0();
    BAR();

    int slot = 0;
    for (int kt = 0; kt < KTILES; ++kt) {
        const bool nx = (kt + 1 < KTILES);

        // ---- frag reads FIRST (vmcnt already 0 here -> no forced drain) ----
        union Frag { u32x4 q[2]; i32x8 v; };
        i32x8 af[4], bf[2];
        #pragma unroll
        for (int fi = 0; fi < 4; ++fi) {
            const int r = wm * 128 + fi * 32 + l31;
            Frag fa;
            fa.q[0] = Abuf[slot][unit_of(r, 2 * h)];
            fa.q[1] = Abuf[slot][unit_of(r, 2 * h + 1)];
            af[fi] = fa.v;
        }
        #pragma unroll
        for (int cf = 0; cf < 2; ++cf) {
            const int r = wn * 64 + cf * 32 + l31;
            Frag fb;
            fb.q[0] = Bbuf[slot][unit_of(r, 2 * h)];
            fb.q[1] = Bbuf[slot][unit_of(r, 2 * h + 1)];
            bf[cf] = fb.v;
        }

        // ---- stage kt+1 AFTER the reads (flight hides under MFMAs) ----
        if (nx) STAGE_TILE(slot ^ 1, kt + 1);

        __builtin_amdgcn_s_setprio(1);
        #pragma unroll
        for (int fi = 0; fi < 4; ++fi)
            #pragma unroll
            for (int cf = 0; cf < 2; ++cf)
                acc[fi][cf] = __builtin_amdgcn_mfma_scale_f32_32x32x64_f8f6f4(
                    af[fi], bf[cf], acc[fi][cf], 0, 0,
                    0, 0x7F7F7F7F, 0, 0x7F7F7F7F);   // fmt=fp8, scales=1.0
        __builtin_amdgcn_s_setprio(0);

        if (nx) {
            WAITVM0();      // drain stage(kt+1) after MFMA issue window
            BAR();
        }
        slot ^= 1;
    }
#undef STAGE_TILE

    // ---- epilogue ----
    // C/D 32x32 layout (m74/m101): col = lane&31, row = (v&3)+8*(v>>2)+4*(lane>>5)
    float cspart[2] = {0.0f, 0.0f};
    #pragma unroll
    for (int fi = 0; fi < 4; ++fi) {
        float rpart[16];
        #pragma unroll
        for (int v = 0; v < 16; ++v) rpart[v] = 0.0f;
        #pragma unroll
        for (int cf = 0; cf < 2; ++cf) {
            const int gcol = colBase + wn * 64 + cf * 32 + l31;
            #pragma unroll
            for (int v = 0; v < 16; ++v) {
                const int grow = rowBase + wm * 128 + fi * 32
                               + (v & 3) + 8 * (v >> 2) + 4 * h;
                const float tv = acc[fi][cf][v] * LOGIT_SCALE;
                if (gcol == grow + 1 && ((grow & 1) == 0)) {
                    tgt[grow] = tv; tgt[grow + 1] = tv;   // sim symmetric
                }
                const float ev = (gcol > grow) ? __expf(tv) : 0.0f;
                rpart[v] += ev;
                cspart[cf] += ev;
            }
        }
        // row sums: reduce over the 32 columns (lanes sharing l>>5)
        #pragma unroll
        for (int m = 1; m < 32; m <<= 1) {
            #pragma unroll
            for (int v = 0; v < 16; ++v) rpart[v] += __shfl_xor(rpart[v], m, 64);
        }
        if (l31 == 0) {
            float* dst = rs + (size_t)(jc * 2 + wn) * N_ROWS;
            #pragma unroll
            for (int v = 0; v < 16; ++v)
                dst[rowBase + wm * 128 + fi * 32 + (v & 3) + 8 * (v >> 2) + 4 * h]
                    = rpart[v];
        }
    }
    // column sums (mirror): combine lane halves, lanes 0-31 write
    #pragma unroll
    for (int cf = 0; cf < 2; ++cf) {
        cspart[cf] += __shfl_xor(cspart[cf], 32, 64);
        if (lane < 32)
            cs[(size_t)(rt * 2 + wm) * N_ROWS + colBase + wn * 64 + cf * 32 + l31]
                = cspart[cf];
    }
}

// ------------- Kernel 3: per-row LSE - target logit --------------------------
// row x: rs planes jc*2+{0,1} for jc >= 2*(x>>8); cs planes rt*2+{0,1} for
// rt <= (x>>7)/2  (exactly the tiles that exist for this row/col).
__global__ __launch_bounds__(256) void row_term_kernel(
    const float* __restrict__ rs, const float* __restrict__ cs,
    const float* __restrict__ tgt, float* __restrict__ terms)
{
    const int row = blockIdx.x * 256 + threadIdx.x;
    const int P = row >> 8, jcx = row >> 7;
    float s = 0.0f;
    for (int jc = 2 * P; jc < NJC; ++jc) {
        const float* b = rs + (size_t)(jc * 2) * N_ROWS + row;
        s += b[0] + b[N_ROWS];
    }
    for (int rt = 0; rt <= (jcx >> 1); ++rt) {
        const float* b = cs + (size_t)(rt * 2) * N_ROWS + row;
        s += b[0] + b[N_ROWS];
    }
    terms[row] = logf(s) - tgt[row];
}

// ------------- Kernel 4: mean over rows --------------------------------------
__global__ __launch_bounds__(1024) void loss_kernel(
    const float* __restrict__ terms, float* __restrict__ out)
{
    const int t = threadIdx.x;
    float s = 0.0f;
    for (int i = t; i < N_ROWS; i += 1024) s += terms[i];
    #pragma unroll
    for (int m = 1; m < 64; m <<= 1) s += __shfl_xor(s, m, 64);
    __shared__ float red[16];
    if ((t & 63) == 0) red[t >> 6] = s;
    __syncthreads();
    if (t == 0) {
        float tot = 0.0f;
        #pragma unroll
        for (int i = 0; i < 16; ++i) tot += red[i];
        out[0] = tot * (1.0f / N_ROWS);
    }
}

extern "C" void kernel_launch(void* const* d_in, const int* in_sizes, int n_in,
                              void* d_out, int out_size, void* d_ws, size_t ws_size,
                              hipStream_t stream)
{
    const float* z_i = (const float*)d_in[0];
    const float* z_j = (const float*)d_in[1];
    float* out = (float*)d_out;

    // workspace layout
    unsigned char* xn8 = (unsigned char*)d_ws;                        // 8 MiB fp8
    float* rs    = (float*)(xn8 + (size_t)N_ROWS * DIMK);             // 4 MiB
    float* cs    = rs + (size_t)128 * N_ROWS;                         // 2 MiB
    float* tgt   = cs + (size_t)64 * N_ROWS;                          // 32 KiB
    float* terms = tgt + N_ROWS;                                      // 32 KiB

    norm_rows_kernel<<<N_ROWS / 4, 256, 0, stream>>>(z_i, z_j, (unsigned int*)xn8);
    simexp_kernel<<<NTILES, 256, 0, stream>>>(xn8, rs, cs, tgt);
    row_term_kernel<<<N_ROWS / 256, 256, 0, stream>>>(rs, cs, tgt, terms);
    loss_kernel<<<1, 1024, 0, stream>>>(terms, out);
}